// Round 1
// baseline (34.936 us; speedup 1.0000x reference)
//
#include <hip/hip_runtime.h>
#include <math.h>

#define B_ 128
#define K_ 2048
#define TEMP_ 0.07f
#define EPS_ 1e-12f

// ---------------------------------------------------------------------------
// K1: row-wise L2 normalize: f[i,:] = feat[i,:] / max(||feat[i,:]||, EPS)
// 128 blocks x 256 threads; 2048 floats/row = 512 float4, 2 per thread.
// ---------------------------------------------------------------------------
__global__ __launch_bounds__(256) void k_norm(const float* __restrict__ feat,
                                              float* __restrict__ f) {
    const int i = blockIdx.x;
    const int tid = threadIdx.x;
    const float4* src = reinterpret_cast<const float4*>(feat + (size_t)i * K_);
    float4* dst = reinterpret_cast<float4*>(f + (size_t)i * K_);
    float4 v0 = src[tid];
    float4 v1 = src[tid + 256];
    float s = v0.x * v0.x + v0.y * v0.y + v0.z * v0.z + v0.w * v0.w
            + v1.x * v1.x + v1.y * v1.y + v1.z * v1.z + v1.w * v1.w;
#pragma unroll
    for (int o = 1; o < 64; o <<= 1) s += __shfl_xor(s, o, 64);
    __shared__ float wsum[4];
    const int wave = tid >> 6, lane = tid & 63;
    if (lane == 0) wsum[wave] = s;
    __syncthreads();
    const float tot = wsum[0] + wsum[1] + wsum[2] + wsum[3];
    const float rn = 1.0f / fmaxf(sqrtf(tot), EPS_);
    v0.x *= rn; v0.y *= rn; v0.z *= rn; v0.w *= rn;
    v1.x *= rn; v1.y *= rn; v1.z *= rn; v1.w *= rn;
    dst[tid] = v0;
    dst[tid + 256] = v1;
}

// ---------------------------------------------------------------------------
// K2: pair kernel. 512 blocks: blk = i*4 + jq (j-quarter of 32 rows).
// 256 threads = 4 waves; wave w handles j = jq*32 + w*8 + t, t=0..7.
// LDS: f_i, g_i = 1+f_i^3, h_i = f_i^2  (each 8 KB).
// Per pair: 4 reductions over k (f.u, u.u, f.v, v.v), butterfly shfl.
// Writes per-(i,quarter) partials: sum_j d_self, sum_j (e^ds + 3 e^do).
// ---------------------------------------------------------------------------
__global__ __launch_bounds__(256) void k_pairs(const float* __restrict__ f,
                                               float* __restrict__ part) {
    const int blk = blockIdx.x;
    const int i = blk >> 2;
    const int jq = blk & 3;
    const int tid = threadIdx.x;
    const int wave = tid >> 6, lane = tid & 63;

    __shared__ float sfi[K_];
    __shared__ float sg[K_];
    __shared__ float sh[K_];
    {
        const float4* fi4 = reinterpret_cast<const float4*>(f + (size_t)i * K_);
        float4* a4 = reinterpret_cast<float4*>(sfi);
        float4* g4 = reinterpret_cast<float4*>(sg);
        float4* h4 = reinterpret_cast<float4*>(sh);
#pragma unroll
        for (int t = 0; t < 2; ++t) {
            const int idx = tid + t * 256;
            float4 a = fi4[idx];
            float4 g, h;
            h.x = a.x * a.x; h.y = a.y * a.y; h.z = a.z * a.z; h.w = a.w * a.w;
            g.x = 1.0f + h.x * a.x; g.y = 1.0f + h.y * a.y;
            g.z = 1.0f + h.z * a.z; g.w = 1.0f + h.w * a.w;
            a4[idx] = a; g4[idx] = g; h4[idx] = h;
        }
    }
    __syncthreads();

    const float4* a4 = reinterpret_cast<const float4*>(sfi);
    const float4* g4 = reinterpret_cast<const float4*>(sg);
    const float4* h4 = reinterpret_cast<const float4*>(sh);

    float s1 = 0.0f, s2 = 0.0f;

#pragma unroll 1
    for (int t = 0; t < 8; ++t) {
        const int j = jq * 32 + wave * 8 + t;
        const float4* fj4 = reinterpret_cast<const float4*>(f + (size_t)j * K_);
        float du = 0.0f, uu = 0.0f, dv = 0.0f, vv = 0.0f;
#pragma unroll
        for (int c = 0; c < 8; ++c) {
            const int idx = c * 64 + lane;
            const float4 a = a4[idx];
            const float4 g = g4[idx];
            const float4 h = h4[idx];
            const float4 b = fj4[idx];
#define ACC1(AX, GX, HX, BX)                                \
            {                                               \
                const float u = (BX) * (GX);                \
                du = fmaf((AX), u, du);                     \
                uu = fmaf(u, u, uu);                        \
                const float t0 = (HX) * (BX);               \
                const float v = fmaf(t0, (BX), (BX));       \
                dv = fmaf((AX), v, dv);                     \
                vv = fmaf(v, v, vv);                        \
            }
            ACC1(a.x, g.x, h.x, b.x)
            ACC1(a.y, g.y, h.y, b.y)
            ACC1(a.z, g.z, h.z, b.z)
            ACC1(a.w, g.w, h.w, b.w)
#undef ACC1
        }
#pragma unroll
        for (int o = 1; o < 64; o <<= 1) {
            du += __shfl_xor(du, o, 64);
            uu += __shfl_xor(uu, o, 64);
            dv += __shfl_xor(dv, o, 64);
            vv += __shfl_xor(vv, o, 64);
        }
        const float inv_t = 1.0f / TEMP_;
        const float ds = du / fmaxf(sqrtf(uu), EPS_) * inv_t;
        const float dn = dv / fmaxf(sqrtf(vv), EPS_) * inv_t;
        s1 += ds;
        s2 += __expf(ds) + 3.0f * __expf(dn);
    }

    __shared__ float p1[4], p2[4];
    if (lane == 0) { p1[wave] = s1; p2[wave] = s2; }
    __syncthreads();
    if (tid == 0) {
        part[blk * 2 + 0] = p1[0] + p1[1] + p1[2] + p1[3];
        part[blk * 2 + 1] = p2[0] + p2[1] + p2[2] + p2[3];
    }
}

// ---------------------------------------------------------------------------
// K3: final. thread i combines its 4 quarter-partials, computes
// contrib_i = (1/B) * sum_j d_self - log(denom_i), then reduces over i.
// loss = -(1/B) * sum_i contrib_i
// ---------------------------------------------------------------------------
__global__ __launch_bounds__(128) void k_final(const float* __restrict__ part,
                                               float* __restrict__ out) {
    const int i = threadIdx.x;
    float s1 = 0.0f, s2 = 0.0f;
#pragma unroll
    for (int q = 0; q < 4; ++q) {
        s1 += part[(i * 4 + q) * 2 + 0];
        s2 += part[(i * 4 + q) * 2 + 1];
    }
    float c = s1 * (1.0f / B_) - __logf(s2);
#pragma unroll
    for (int o = 1; o < 64; o <<= 1) c += __shfl_xor(c, o, 64);
    __shared__ float wsum[2];
    const int wave = i >> 6, lane = i & 63;
    if (lane == 0) wsum[wave] = c;
    __syncthreads();
    if (i == 0) out[0] = -(wsum[0] + wsum[1]) * (1.0f / B_);
}

extern "C" void kernel_launch(void* const* d_in, const int* in_sizes, int n_in,
                              void* d_out, int out_size, void* d_ws, size_t ws_size,
                              hipStream_t stream) {
    const float* feat = (const float*)d_in[0];
    float* f = (float*)d_ws;                 // 128*2048 floats = 1 MB
    float* part = f + (size_t)B_ * K_;       // 512*2 floats
    float* out = (float*)d_out;

    k_norm<<<B_, 256, 0, stream>>>(feat, f);
    k_pairs<<<512, 256, 0, stream>>>(f, part);
    k_final<<<1, 128, 0, stream>>>(part, out);
}

// Round 2
// 24.768 us; speedup vs baseline: 1.4106x; 1.4106x over previous
//
#include <hip/hip_runtime.h>
#include <math.h>

#define B_ 128
#define K_ 2048
#define TEMP_ 0.07f
#define EPS_ 1e-12f

// ---------------------------------------------------------------------------
// K1: row-wise L2 normalize: f[i,:] = feat[i,:] / max(||feat[i,:]||, EPS)
// ---------------------------------------------------------------------------
__global__ __launch_bounds__(256) void k_norm(const float* __restrict__ feat,
                                              float* __restrict__ f) {
    const int i = blockIdx.x;
    const int tid = threadIdx.x;
    const float4* src = reinterpret_cast<const float4*>(feat + (size_t)i * K_);
    float4* dst = reinterpret_cast<float4*>(f + (size_t)i * K_);
    float4 v0 = src[tid];
    float4 v1 = src[tid + 256];
    float s = v0.x * v0.x + v0.y * v0.y + v0.z * v0.z + v0.w * v0.w
            + v1.x * v1.x + v1.y * v1.y + v1.z * v1.z + v1.w * v1.w;
#pragma unroll
    for (int o = 1; o < 64; o <<= 1) s += __shfl_xor(s, o, 64);
    __shared__ float wsum[4];
    const int wave = tid >> 6, lane = tid & 63;
    if (lane == 0) wsum[wave] = s;
    __syncthreads();
    const float tot = wsum[0] + wsum[1] + wsum[2] + wsum[3];
    const float rn = 1.0f / fmaxf(sqrtf(tot), EPS_);
    v0.x *= rn; v0.y *= rn; v0.z *= rn; v0.w *= rn;
    v1.x *= rn; v1.y *= rn; v1.z *= rn; v1.w *= rn;
    dst[tid] = v0;
    dst[tid + 256] = v1;
}

// ---------------------------------------------------------------------------
// K2: pair kernel, v2.
// Grid 1024: blk = i*8 + jg (jg = group of 16 j's). 256 threads = 4 waves.
// Wave w handles 4 j's: j = jg*16 + w*4 + {0..3}, all in one batch —
// a/g/h LDS reads amortized over 4 j's, no outer j loop, 4 blocks/CU.
// ---------------------------------------------------------------------------
__global__ __launch_bounds__(256, 4) void k_pairs(const float* __restrict__ f,
                                                  float* __restrict__ part) {
    const int blk = blockIdx.x;
    const int i = blk >> 3;
    const int jg = blk & 7;
    const int tid = threadIdx.x;
    const int wave = tid >> 6, lane = tid & 63;

    __shared__ float sa[K_];
    __shared__ float sg[K_];
    __shared__ float sh[K_];
    {
        const float4* fi4 = reinterpret_cast<const float4*>(f + (size_t)i * K_);
        float4* a4 = reinterpret_cast<float4*>(sa);
        float4* g4 = reinterpret_cast<float4*>(sg);
        float4* h4 = reinterpret_cast<float4*>(sh);
#pragma unroll
        for (int t = 0; t < 2; ++t) {
            const int idx = tid + t * 256;
            float4 a = fi4[idx];
            float4 g, h;
            h.x = a.x * a.x; h.y = a.y * a.y; h.z = a.z * a.z; h.w = a.w * a.w;
            g.x = 1.0f + h.x * a.x; g.y = 1.0f + h.y * a.y;
            g.z = 1.0f + h.z * a.z; g.w = 1.0f + h.w * a.w;
            a4[idx] = a; g4[idx] = g; h4[idx] = h;
        }
    }
    __syncthreads();

    const int j0 = jg * 16 + wave * 4;
    const float4* b0 = reinterpret_cast<const float4*>(f + (size_t)(j0 + 0) * K_);
    const float4* b1 = reinterpret_cast<const float4*>(f + (size_t)(j0 + 1) * K_);
    const float4* b2 = reinterpret_cast<const float4*>(f + (size_t)(j0 + 2) * K_);
    const float4* b3 = reinterpret_cast<const float4*>(f + (size_t)(j0 + 3) * K_);

    const float4* a4 = reinterpret_cast<const float4*>(sa);
    const float4* g4 = reinterpret_cast<const float4*>(sg);
    const float4* h4 = reinterpret_cast<const float4*>(sh);

    float du[4] = {0.f, 0.f, 0.f, 0.f};
    float uu[4] = {0.f, 0.f, 0.f, 0.f};
    float dv[4] = {0.f, 0.f, 0.f, 0.f};
    float vv[4] = {0.f, 0.f, 0.f, 0.f};

#pragma unroll
    for (int c = 0; c < 8; ++c) {
        const int idx = c * 64 + lane;
        const float4 a = a4[idx];
        const float4 g = g4[idx];
        const float4 h = h4[idx];
        float4 bb[4];
        bb[0] = b0[idx]; bb[1] = b1[idx]; bb[2] = b2[idx]; bb[3] = b3[idx];
#pragma unroll
        for (int t = 0; t < 4; ++t) {
#define ACC1(AX, GX, HX, BX)                                \
            {                                               \
                const float u = (BX) * (GX);                \
                du[t] = fmaf((AX), u, du[t]);               \
                uu[t] = fmaf(u, u, uu[t]);                  \
                const float t0 = (HX) * (BX);               \
                const float v = fmaf(t0, (BX), (BX));       \
                dv[t] = fmaf((AX), v, dv[t]);               \
                vv[t] = fmaf(v, v, vv[t]);                  \
            }
            ACC1(a.x, g.x, h.x, bb[t].x)
            ACC1(a.y, g.y, h.y, bb[t].y)
            ACC1(a.z, g.z, h.z, bb[t].z)
            ACC1(a.w, g.w, h.w, bb[t].w)
#undef ACC1
        }
    }

#pragma unroll
    for (int o = 1; o < 64; o <<= 1) {
#pragma unroll
        for (int t = 0; t < 4; ++t) {
            du[t] += __shfl_xor(du[t], o, 64);
            uu[t] += __shfl_xor(uu[t], o, 64);
            dv[t] += __shfl_xor(dv[t], o, 64);
            vv[t] += __shfl_xor(vv[t], o, 64);
        }
    }

    const float inv_t = 1.0f / TEMP_;
    float s1 = 0.f, s2 = 0.f;
#pragma unroll
    for (int t = 0; t < 4; ++t) {
        const float ds = du[t] / fmaxf(sqrtf(uu[t]), EPS_) * inv_t;
        const float dn = dv[t] / fmaxf(sqrtf(vv[t]), EPS_) * inv_t;
        s1 += ds;
        s2 += __expf(ds) + 3.0f * __expf(dn);
    }

    __shared__ float p1[4], p2[4];
    if (lane == 0) { p1[wave] = s1; p2[wave] = s2; }
    __syncthreads();
    if (tid == 0) {
        part[blk * 2 + 0] = p1[0] + p1[1] + p1[2] + p1[3];
        part[blk * 2 + 1] = p2[0] + p2[1] + p2[2] + p2[3];
    }
}

// ---------------------------------------------------------------------------
// K3: final. thread i combines its 8 group-partials, computes
// contrib_i = (1/B) * sum_j d_self - log(denom_i), reduces over i.
// ---------------------------------------------------------------------------
__global__ __launch_bounds__(128) void k_final(const float* __restrict__ part,
                                               float* __restrict__ out) {
    const int i = threadIdx.x;
    float s1 = 0.0f, s2 = 0.0f;
#pragma unroll
    for (int q = 0; q < 8; ++q) {
        s1 += part[(i * 8 + q) * 2 + 0];
        s2 += part[(i * 8 + q) * 2 + 1];
    }
    float c = s1 * (1.0f / B_) - __logf(s2);
#pragma unroll
    for (int o = 1; o < 64; o <<= 1) c += __shfl_xor(c, o, 64);
    __shared__ float wsum[2];
    const int wave = i >> 6, lane = i & 63;
    if (lane == 0) wsum[wave] = c;
    __syncthreads();
    if (i == 0) out[0] = -(wsum[0] + wsum[1]) * (1.0f / B_);
}

extern "C" void kernel_launch(void* const* d_in, const int* in_sizes, int n_in,
                              void* d_out, int out_size, void* d_ws, size_t ws_size,
                              hipStream_t stream) {
    const float* feat = (const float*)d_in[0];
    float* f = (float*)d_ws;                 // 128*2048 floats = 1 MB
    float* part = f + (size_t)B_ * K_;       // 1024*2 floats
    float* out = (float*)d_out;

    k_norm<<<B_, 256, 0, stream>>>(feat, f);
    k_pairs<<<1024, 256, 0, stream>>>(f, part);
    k_final<<<1, 128, 0, stream>>>(part, out);
}